// Round 3
// baseline (3517.375 us; speedup 1.0000x reference)
//
#include <hip/hip_runtime.h>
#include <hip/hip_fp16.h>

typedef unsigned int uint32;
typedef __attribute__((ext_vector_type(4))) uint32 u32x4;
typedef __attribute__((ext_vector_type(8))) _Float16 half8;
typedef __attribute__((ext_vector_type(4))) float f32x4;

#define T_STEPS 512
#define BSZ 128
#define ISZ 256
#define HSZ 512
#define K1  768            // H + I, concat order (h, x)
#define NG  8              // batch groups
#define BG  16             // batch rows per group
#define GC  32             // workgroups per group (column partition)
#define NC  16             // H-columns per workgroup
#define LDK 776            // padded K stride (fp16 elems), %8==0 for half8 LDS reads

// LDS layout (bytes)
#define LDS_A   0          // A tile [16][LDK] fp16  (h|x or rh|x)
#define LDS_WZ  24832
#define LDS_WR  49664
#define LDS_WH  74496
#define LDS_SR0 99328      // r/cand partials, even steps  [4][16*17] f32
#define LDS_SR1 103680     // r/cand partials, odd steps
#define LDS_SZ  108032     // z partials
#define SMEM_BYTES 112384

__device__ __forceinline__ float sigm(float x) {
  float e = __expf(-fabsf(x));
  float s = 1.f / (1.f + e);
  return x >= 0.f ? s : 1.f - s;
}
__device__ __forceinline__ float tanhx(float x) {
  float e = __expf(-2.f * fabsf(x));
  float t = (1.f - e) / (1.f + e);
  return x >= 0.f ? t : -t;
}
__device__ __forceinline__ uint32 f2x(float a, float b) {
  __half2 t = __floats2half2_rn(a, b);
  return *reinterpret_cast<uint32*>(&t);
}

// 8 x dwordx4 IC loads (bypass L1+L2 via sc0 sc1), single waitcnt
__device__ __forceinline__ void ld8_ic(const uint32* p, u32x4 v[8]) {
  asm volatile(
    "global_load_dwordx4 %0, %8, off offset:0 sc0 sc1\n\t"
    "global_load_dwordx4 %1, %8, off offset:16 sc0 sc1\n\t"
    "global_load_dwordx4 %2, %8, off offset:32 sc0 sc1\n\t"
    "global_load_dwordx4 %3, %8, off offset:48 sc0 sc1\n\t"
    "global_load_dwordx4 %4, %8, off offset:64 sc0 sc1\n\t"
    "global_load_dwordx4 %5, %8, off offset:80 sc0 sc1\n\t"
    "global_load_dwordx4 %6, %8, off offset:96 sc0 sc1\n\t"
    "global_load_dwordx4 %7, %8, off offset:112 sc0 sc1\n\t"
    "s_waitcnt vmcnt(0)"
    : "=v"(v[0]), "=v"(v[1]), "=v"(v[2]), "=v"(v[3]),
      "=v"(v[4]), "=v"(v[5]), "=v"(v[6]), "=v"(v[7])
    : "v"(p)
    : "memory");
}
// fire-and-forget IC store (no drain)
__device__ __forceinline__ void st_ic(uint32* p, uint32 d) {
  asm volatile("global_store_dword %0, %1, off sc0 sc1" :: "v"(p), "v"(d) : "memory");
}

// poll 32 tagged dwords until all carry `want` in high 16, then unpack fp16
// payloads into 32 consecutive halves at dstA
__device__ __forceinline__ void poll_stage(const uint32* src, _Float16* dstA, uint32 want) {
  const uint32 wtag = want << 16;
  u32x4 v[8];
  for (;;) {
    ld8_ic(src, v);
    uint32 d = 0;
    #pragma unroll
    for (int i = 0; i < 8; ++i)
      d |= (v[i].x ^ wtag) | (v[i].y ^ wtag) | (v[i].z ^ wtag) | (v[i].w ^ wtag);
    if ((d & 0xFFFF0000u) == 0) break;
  }
  uint4* hd = (uint4*)dstA;
  #pragma unroll
  for (int i = 0; i < 4; ++i) {
    u32x4 a = v[2 * i], b = v[2 * i + 1];
    hd[i] = make_uint4((a.x & 0xFFFFu) | (a.y << 16),
                       (a.z & 0xFFFFu) | (a.w << 16),
                       (b.x & 0xFFFFu) | (b.y << 16),
                       (b.z & 0xFFFFu) | (b.w << 16));
  }
}

__global__ __launch_bounds__(256, 1)
void gru_persist(const float* __restrict__ x,
                 const float* __restrict__ Wz, const float* __restrict__ bz,
                 const float* __restrict__ Wr, const float* __restrict__ br,
                 const float* __restrict__ Wh, const float* __restrict__ bh,
                 float* __restrict__ out,
                 uint32* hT, uint32* rhT)
{
  extern __shared__ char smem[];
  _Float16* A_l  = (_Float16*)(smem + LDS_A);
  _Float16* Wz_l = (_Float16*)(smem + LDS_WZ);
  _Float16* Wr_l = (_Float16*)(smem + LDS_WR);
  _Float16* Wh_l = (_Float16*)(smem + LDS_WH);
  float*    sR0  = (float*)(smem + LDS_SR0);
  float*    sR1  = (float*)(smem + LDS_SR1);
  float*    sZ   = (float*)(smem + LDS_SZ);

  const int tid  = threadIdx.x;
  const int g    = blockIdx.x & 7;
  const int rank = blockIdx.x >> 3;
  uint32* hTG  = hT  + (size_t)g * BG * HSZ;   // tagged [16][512] dwords
  uint32* rhTG = rhT + (size_t)g * BG * HSZ;

  // ---- one-time: weight slices -> LDS fp16 ----
  {
    const int r  = tid & 15;
    const int ch = tid >> 4;
    for (int mi = 0; mi < 3; ++mi) {
      const float* Ws = (mi == 0) ? Wz : (mi == 1 ? Wr : Wh);
      _Float16*    Ld = (mi == 0) ? Wz_l : (mi == 1 ? Wr_l : Wh_l);
      const float4* s = (const float4*)(Ws + (size_t)(rank * NC + r) * K1 + ch * 48);
      uint4* d = (uint4*)(Ld + r * LDK + ch * 48);
      #pragma unroll
      for (int j = 0; j < 6; ++j) {
        float4 v0 = s[2 * j], v1 = s[2 * j + 1];
        d[j] = make_uint4(f2x(v0.x, v0.y), f2x(v0.z, v0.w),
                          f2x(v1.x, v1.y), f2x(v1.z, v1.w));
      }
    }
  }

  const int cl = tid & 15, bl = tid >> 4;      // elementwise: (batch bl, col cl)
  const int bl2 = tid & 15, cl2 = tid >> 4;    // staging: lane->row (2-way-free LDS)
  const int cg = rank * NC + cl;
  const int bg = g * BG + bl;
  const int bg2 = g * BG + bl2;
  const float bz_r = bz[cg], br_r = br[cg], bh_r = bh[cg];

  float h_reg = 0.f, zg = 0.f;

  float4 px0, px1, px2, px3;                   // x[t] slice: row bl2, I-cols cl2*16..+16
  {
    const float4* xs = (const float4*)(x + (size_t)bg2 * ISZ + cl2 * 16);
    px0 = xs[0]; px1 = xs[1]; px2 = xs[2]; px3 = xs[3];
  }

  const int wv = tid >> 6, lane = tid & 63;
  const int mrow = lane & 15, q = lane >> 4;
  const int scO = bl * 17 + cl;

  for (int t = 0; t < T_STEPS; ++t) {
    float* scR = (t & 1) ? sR1 : sR0;

    // ---- (A) stage x_t -> A[:,512:768); reload px <- x[t+1] ----
    {
      uint4* xd = (uint4*)(A_l + bl2 * LDK + HSZ + cl2 * 16);
      xd[0] = make_uint4(f2x(px0.x, px0.y), f2x(px0.z, px0.w),
                         f2x(px1.x, px1.y), f2x(px1.z, px1.w));
      xd[1] = make_uint4(f2x(px2.x, px2.y), f2x(px2.z, px2.w),
                         f2x(px3.x, px3.y), f2x(px3.z, px3.w));
      if (t + 1 < T_STEPS) {
        const float4* xs = (const float4*)(x + ((size_t)(t + 1) * BSZ + bg2) * ISZ + cl2 * 16);
        px0 = xs[0]; px1 = xs[1]; px2 = xs[2]; px3 = xs[3];
      }
    }
    // ---- (B) poll+stage h_{t-1} (seq 2t) -> A[:,0:512) ----
    poll_stage(hTG + bl2 * HSZ + cl2 * 32, A_l + bl2 * LDK + cl2 * 32, (uint32)(2 * t));
    __syncthreads();                                          // B1

    // ---- (C) r GEMM, all 4 waves, K=768 4-way ----
    {
      const int kb = wv * 192;
      const half8* Ap = (const half8*)(A_l  + mrow * LDK + kb) + q;
      const half8* Bp = (const half8*)(Wr_l + mrow * LDK + kb) + q;
      f32x4 a = {0.f, 0.f, 0.f, 0.f};
      #pragma unroll
      for (int kk = 0; kk < 6; ++kk)
        a = __builtin_amdgcn_mfma_f32_16x16x32_f16(Ap[kk * 4], Bp[kk * 4], a, 0, 0, 0);
      float* s = scR + wv * 272;
      #pragma unroll
      for (int i = 0; i < 4; ++i) s[(q * 4 + i) * 17 + mrow] = a[i];
    }
    __syncthreads();                                          // B2

    // ---- (D) r elementwise; publish rh tagged (2t+1) — no drain, no barrier ----
    {
      float rp = scR[scO] + scR[272 + scO] + scR[544 + scO] + scR[816 + scO] + br_r;
      float rhv = sigm(rp) * h_reg;
      uint32 w = (uint32)__half_as_ushort(__float2half(rhv)) | ((uint32)(2 * t + 1) << 16);
      st_ic(rhTG + bl * HSZ + cg, w);
    }

    // ---- (E) z GEMM (4-way) + cand x-part (overlaps rh flight) ----
    f32x4 acc2 = {0.f, 0.f, 0.f, 0.f};
    {
      const int kb = wv * 192;
      const half8* Ap = (const half8*)(A_l  + mrow * LDK + kb) + q;
      const half8* Bp = (const half8*)(Wz_l + mrow * LDK + kb) + q;
      f32x4 a = {0.f, 0.f, 0.f, 0.f};
      #pragma unroll
      for (int kk = 0; kk < 6; ++kk)
        a = __builtin_amdgcn_mfma_f32_16x16x32_f16(Ap[kk * 4], Bp[kk * 4], a, 0, 0, 0);
      float* s = sZ + wv * 272;
      #pragma unroll
      for (int i = 0; i < 4; ++i) s[(q * 4 + i) * 17 + mrow] = a[i];
      const int kb2 = HSZ + wv * 64;
      const half8* Ap2 = (const half8*)(A_l  + mrow * LDK + kb2) + q;
      const half8* Bp2 = (const half8*)(Wh_l + mrow * LDK + kb2) + q;
      #pragma unroll
      for (int kk = 0; kk < 2; ++kk)
        acc2 = __builtin_amdgcn_mfma_f32_16x16x32_f16(Ap2[kk * 4], Bp2[kk * 4], acc2, 0, 0, 0);
    }
    __syncthreads();                                          // B3

    // ---- (F) z elementwise ----
    zg = sigm(sZ[scO] + sZ[272 + scO] + sZ[544 + scO] + sZ[816 + scO] + bz_r);

    // ---- (G) poll+stage rh (seq 2t+1) -> A[:,0:512) ----
    poll_stage(rhTG + bl2 * HSZ + cl2 * 32, A_l + bl2 * LDK + cl2 * 32, (uint32)(2 * t + 1));
    __syncthreads();                                          // B4

    // ---- (H) cand h-part GEMM (4-way over K=512) ----
    {
      const int kb = wv * 128;
      const half8* Ap = (const half8*)(A_l  + mrow * LDK + kb) + q;
      const half8* Bp = (const half8*)(Wh_l + mrow * LDK + kb) + q;
      #pragma unroll
      for (int kk = 0; kk < 4; ++kk)
        acc2 = __builtin_amdgcn_mfma_f32_16x16x32_f16(Ap[kk * 4], Bp[kk * 4], acc2, 0, 0, 0);
      float* s = scR + wv * 272;
      #pragma unroll
      for (int i = 0; i < 4; ++i) s[(q * 4 + i) * 17 + mrow] = acc2[i];
    }
    __syncthreads();                                          // B5

    // ---- (I) cand, h update, publish h tagged (2t+2), out store ----
    {
      float cp = scR[scO] + scR[272 + scO] + scR[544 + scO] + scR[816 + scO] + bh_r;
      float cand = tanhx(cp);
      float hn = (1.f - zg) * h_reg + zg * cand;
      h_reg = hn;
      uint32 w = (uint32)__half_as_ushort(__float2half(hn)) | ((uint32)(2 * t + 2) << 16);
      st_ic(hTG + bl * HSZ + cg, w);
      out[((size_t)t * BSZ + bg) * HSZ + cg] = hn;
      if (t == T_STEPS - 1)
        out[((size_t)T_STEPS * BSZ + bg) * HSZ + cg] = hn;   // h_last
    }
    // no end barrier: next (A)/(B) touch regions last read before B5/B2;
    // scR alternates by parity so next (C) won't clobber what (I) reads.
  }
}

extern "C" void kernel_launch(void* const* d_in, const int* in_sizes, int n_in,
                              void* d_out, int out_size, void* d_ws, size_t ws_size,
                              hipStream_t stream) {
  const float* x  = (const float*)d_in[0];
  const float* Wz = (const float*)d_in[1];
  const float* bz = (const float*)d_in[2];
  const float* Wr = (const float*)d_in[3];
  const float* br = (const float*)d_in[4];
  const float* Wh = (const float*)d_in[5];
  const float* bh = (const float*)d_in[6];
  float* out = (float*)d_out;

  // ws: hT [8][16][512] u32 tagged (256KB), rhT same (256KB)
  uint32* hT  = (uint32*)d_ws;
  uint32* rhT = hT + NG * BG * HSZ;

  // hT = 0 -> payload h0=0 with seq tag 0 (the t=0 expectation).
  // rhT needs no init: first poll expects seq 1; 0xAAAA poison never matches.
  hipMemsetAsync(d_ws, 0, (size_t)NG * BG * HSZ * 4, stream);

  hipFuncSetAttribute(reinterpret_cast<const void*>(gru_persist),
                      hipFuncAttributeMaxDynamicSharedMemorySize, SMEM_BYTES);

  hipLaunchKernelGGL(gru_persist, dim3(NG * GC), dim3(256), SMEM_BYTES, stream,
                     x, Wz, bz, Wr, br, Wh, bh, out, hT, rhT);
}